// Round 2
// baseline (275.223 us; speedup 1.0000x reference)
//
#include <hip/hip_runtime.h>
#include <hip/hip_bf16.h>
#include <cstdint>

// STFT magnitude as fused GEMM, 8-phase counted-vmcnt schedule (T2+T3+T4+T5):
//   out[b,k,t] = sqrt( (basis_r[k,:]·frame[b,t,:])^2 + (basis_i[k,:]·frame[b,t,:])^2 )
// A-"matrix" = [real 1152 rows ; imag 1152 rows] of basis (bf16, ws)
// B-"matrix" = 20224 windowed frames (bf16, ws, reflect pad baked in)
// Block tile: 128 bins x 256 frames, BK=64, 8 waves, 128 KiB LDS dbuf.
// Phase q of K-tile t: ds_read frags(buf b) | stage half q of tile t+1 (buf b^1)
//   | barrier | 16 MFMA. vmcnt(4) at every phase start (2 halves in flight).
// LDS XOR swizzle: granule ^ (row&7); gld_lds dest linear, source pre-swizzled.

#define FILT   2048
#define HOP    512
#define CUT    1025
#define NBATCH 32
#define TFR    626
#define NFR    (NBATCH * TFR)      // 20032
#define LSIG   320000

#define BK 64
#define NK (FILT / BK)             // 32 K-tiles
#define BM 128                     // bins per block
#define BN 256                     // frames per block
#define MT 9
#define NT 79
#define MPAD 1152
#define NPAD (NT * BN)             // 20224
#define NWG (MT * NT)              // 711

typedef __attribute__((ext_vector_type(8))) short short8;
typedef __attribute__((ext_vector_type(4))) float f32x4;

__device__ __forceinline__ short bf16r(float f) {
  __hip_bfloat16 h = __float2bfloat16(f);
  return __builtin_bit_cast(short, h);
}

__device__ __forceinline__ short8 pack8(float4 a, float4 b) {
  short8 v;
  v[0] = bf16r(a.x); v[1] = bf16r(a.y); v[2] = bf16r(a.z); v[3] = bf16r(a.w);
  v[4] = bf16r(b.x); v[5] = bf16r(b.y); v[6] = bf16r(b.z); v[7] = bf16r(b.w);
  return v;
}

__device__ __forceinline__ void gld_lds16(const short* g, short* l) {
  __builtin_amdgcn_global_load_lds(
      (const __attribute__((address_space(1))) uint32_t*)g,
      (__attribute__((address_space(3))) uint32_t*)l, 16, 0, 0);
}

__device__ __forceinline__ void barf() {
  asm volatile("" ::: "memory");
  __builtin_amdgcn_s_barrier();
  asm volatile("" ::: "memory");
}

// -------- stage 1: windowed frames (reflect pad), f32 -> bf16 --------
__global__ void build_frames(const float* __restrict__ x, short* __restrict__ F) {
  const int f = blockIdx.x;                 // 0..NPAD-1
  const size_t base = (size_t)f * FILT;
  const int i = threadIdx.x * 8;            // 256 thr * 8 = 2048
  short8 v;
  if (f >= NFR) {
    v = (short8)(short)0;
  } else {
    const int b = f / TFR, t = f - b * TFR;
    const float* xb = x + (size_t)b * LSIG;
    const int j0 = t * HOP - 1024 + i;
    if (j0 >= 0 && j0 + 8 <= LSIG) {
      float4 a = *(const float4*)(xb + j0);
      float4 c = *(const float4*)(xb + j0 + 4);
      v = pack8(a, c);
    } else {
      #pragma unroll
      for (int e = 0; e < 8; ++e) {
        int j = j0 + e;
        j = j < 0 ? -j : (j >= LSIG ? 2 * LSIG - 2 - j : j);
        v[e] = bf16r(xb[j]);
      }
    }
  }
  *(short8*)&F[base + i] = v;
}

// -------- stage 1b: basis f32 -> bf16, split real/imag, zero-pad rows --------
__global__ void convert_basis(const float* __restrict__ bs, short* __restrict__ A) {
  const int row = blockIdx.x;               // 0..2*MPAD-1
  const int p = row / MPAD;
  const int k = row - p * MPAD;
  const size_t dst = (size_t)row * FILT;
  const int i = threadIdx.x * 8;
  short8 v;
  if (k < CUT) {
    const float* src = bs + (size_t)(p * CUT + k) * FILT + i;
    float4 a = *(const float4*)src;
    float4 c = *(const float4*)(src + 4);
    v = pack8(a, c);
  } else {
    v = (short8)(short)0;
  }
  *(short8*)&A[dst + i] = v;
}

// -------- MFMA helpers --------
__device__ __forceinline__ void mm16(f32x4 acc[4][2], const short8 a[4][2],
                                     const short8 bq[2][2]) {
  __builtin_amdgcn_s_setprio(1);
  #pragma unroll
  for (int m = 0; m < 4; ++m)
    #pragma unroll
    for (int n = 0; n < 2; ++n)
      #pragma unroll
      for (int kk = 0; kk < 2; ++kk)
        acc[m][n] = __builtin_amdgcn_mfma_f32_16x16x32_bf16(a[m][kk], bq[n][kk],
                                                            acc[m][n], 0, 0, 0);
  __builtin_amdgcn_s_setprio(0);
}

// -------- stage 2: fused GEMM + magnitude, 8-phase schedule --------
__global__ __launch_bounds__(512, 2)
void stft_gemm8(const short* __restrict__ Aw, const short* __restrict__ Fw,
                float* __restrict__ out)
{
  __shared__ alignas(16) short sA[2][256][64];   // [buf][plane*128+row][col] 64 KiB
  __shared__ alignas(16) short sB[2][256][64];   // [buf][half*128+row][col]  64 KiB

  const int tid  = threadIdx.x;
  const int wave = tid >> 6;
  const int lane = tid & 63;
  const int wr = wave >> 2;          // 0..1: bin-half of quadrant
  const int wc = wave & 3;           // 0..3: frame slice

  // bijective XCD-aware block swizzle (m204)
  int bid = blockIdx.x;
  { const int q = NWG / 8, r = NWG % 8, xc = bid & 7, o = bid >> 3;
    bid = (xc < r ? xc * (q + 1) : r * (q + 1) + (xc - r) * q) + o; }
  const int by = bid / NT, bx = bid - by * NT;
  const int m0 = by * BM, n0 = bx * BN;

  // ---- staging geometry (pre-swizzled global source, linear LDS dest) ----
  const int lrow = lane >> 3;                 // row within 8-row chunk
  const int soff = ((lane & 7) ^ lrow) * 8;   // swizzled source col (shorts)
  const int ch0 = wave * 2, ch1 = wave * 2 + 1;

  const short* aRow0 = Aw + (size_t)(m0 + ch0 * 8 + lrow) * FILT + soff;
  const short* aRow1 = Aw + (size_t)(m0 + ch1 * 8 + lrow) * FILT + soff;
  const short* bRow0 = Fw + (size_t)(n0 + ch0 * 8 + lrow) * FILT + soff;
  const short* bRow1 = Fw + (size_t)(n0 + ch1 * 8 + lrow) * FILT + soff;
  const size_t planeOff = (size_t)MPAD * FILT;
  const size_t halfOff  = (size_t)128 * FILT;

  auto stageA = [&](int p, int bf, int k0) {
    gld_lds16(aRow0 + (size_t)p * planeOff + k0, &sA[bf][p * 128 + ch0 * 8][0]);
    gld_lds16(aRow1 + (size_t)p * planeOff + k0, &sA[bf][p * 128 + ch1 * 8][0]);
  };
  auto stageB = [&](int h, int bf, int k0) {
    gld_lds16(bRow0 + (size_t)h * halfOff + k0, &sB[bf][h * 128 + ch0 * 8][0]);
    gld_lds16(bRow1 + (size_t)h * halfOff + k0, &sB[bf][h * 128 + ch1 * 8][0]);
  };

  // ---- frag-read geometry (swizzled ds_read) ----
  const int fr = lane & 15;                       // row within 16-frag
  const int fg = lane >> 4;                       // 0..3 col granule group
  const int g0 = ((0 + fg) ^ (lane & 7)) * 8;     // kk=0 swizzled col (shorts)
  const int g1 = ((4 + fg) ^ (lane & 7)) * 8;     // kk=32

  f32x4 acc[4][4][2];   // [q][m][n]; q: 0=(re,bh0) 1=(re,bh1) 2=(im,bh0) 3=(im,bh1)
  #pragma unroll
  for (int q = 0; q < 4; ++q)
    #pragma unroll
    for (int m = 0; m < 4; ++m)
      #pragma unroll
      for (int n = 0; n < 2; ++n) acc[q][m][n] = (f32x4)0.f;

  short8 a[4][2], bq[2][2];

  auto rdA = [&](int p, int bf) {
    #pragma unroll
    for (int m = 0; m < 4; ++m) {
      const int r = p * 128 + wr * 64 + m * 16 + fr;
      a[m][0] = *(const short8*)&sA[bf][r][g0];
      a[m][1] = *(const short8*)&sA[bf][r][g1];
    }
  };
  auto rdB = [&](int h, int bf) {
    #pragma unroll
    for (int n = 0; n < 2; ++n) {
      const int r = h * 128 + wc * 32 + n * 16 + fr;
      bq[n][0] = *(const short8*)&sB[bf][r][g0];
      bq[n][1] = *(const short8*)&sB[bf][r][g1];
    }
  };

  // ---- prologue: tile 0 -> buf 0, order A0,B0,B1,A1 ----
  stageA(0, 0, 0);
  stageB(0, 0, 0);
  stageB(1, 0, 0);
  stageA(1, 0, 0);

  #pragma unroll 2
  for (int t = 0; t < NK; ++t) {
    const int b = t & 1, bn = b ^ 1;
    const int k1 = ((t + 1) & (NK - 1)) * BK;   // wraps on last iter (harmless)

    // phase 0: q0 = (real, frames 0-127)
    asm volatile("s_waitcnt vmcnt(4)" ::: "memory");
    barf();
    rdA(0, b); rdB(0, b);
    stageA(0, bn, k1);
    barf();
    mm16(acc[0], a, bq);

    // phase 1: q1 = (real, frames 128-255), reuse A-frags
    asm volatile("s_waitcnt vmcnt(4)" ::: "memory");
    barf();
    rdB(1, b);
    stageB(0, bn, k1);
    barf();
    mm16(acc[1], a, bq);

    // phase 2: q2 = (imag, frames 0-127)
    asm volatile("s_waitcnt vmcnt(4)" ::: "memory");
    barf();
    rdA(1, b); rdB(0, b);
    stageB(1, bn, k1);
    barf();
    mm16(acc[2], a, bq);

    // phase 3: q3 = (imag, frames 128-255), reuse A-frags
    asm volatile("s_waitcnt vmcnt(4)" ::: "memory");
    barf();
    rdB(1, b);
    stageA(1, bn, k1);
    barf();
    mm16(acc[3], a, bq);
  }
  asm volatile("s_waitcnt vmcnt(0)" ::: "memory");

  // ---- epilogue: magnitude, guarded strided write ----
  const int cl = lane & 15;
  const int rg = (lane >> 4) * 4;
  #pragma unroll
  for (int bh = 0; bh < 2; ++bh) {
    #pragma unroll
    for (int n = 0; n < 2; ++n) {
      const int f = n0 + bh * 128 + wc * 32 + n * 16 + cl;
      if (f >= NFR) continue;
      const int bb = f / TFR, tt = f - bb * TFR;
      float* ob = out + (size_t)bb * (CUT * TFR) + tt;
      #pragma unroll
      for (int m = 0; m < 4; ++m) {
        #pragma unroll
        for (int r = 0; r < 4; ++r) {
          const int k = m0 + wr * 64 + m * 16 + rg + r;
          if (k < CUT) {
            float re = acc[bh][m][n][r];
            float im = acc[2 + bh][m][n][r];
            ob[(size_t)k * TFR] = sqrtf(re * re + im * im);
          }
        }
      }
    }
  }
}

// -------- fallback: reg-staged 128x128 (no ws needed) --------
__global__ __launch_bounds__(256, 2)
void stft_gemm_fb(const float* __restrict__ basis, const float* __restrict__ x,
                  float* __restrict__ out)
{
  __shared__ alignas(16) short sA[2][128][64];
  __shared__ alignas(16) short sB[128][64];

  const int tid  = threadIdx.x;
  const int wave = tid >> 6;
  const int lane = tid & 63;
  const int n0 = blockIdx.x * 128;
  const int m0 = blockIdx.y * 128;

  f32x4 acc_r[4][4], acc_i[4][4];
  #pragma unroll
  for (int i = 0; i < 4; ++i)
    #pragma unroll
    for (int j = 0; j < 4; ++j) { acc_r[i][j] = (f32x4)0.f; acc_i[i][j] = (f32x4)0.f; }

  const int sr = tid >> 1;
  const int sh = (tid & 1) * 32;

  for (int k0 = 0; k0 < FILT; k0 += BK) {
    #pragma unroll
    for (int p = 0; p < 2; ++p) {
      const int k = m0 + sr;
      short8 v[4];
      if (k < CUT) {
        const float* src = basis + (size_t)(p * CUT + k) * FILT + k0 + sh;
        #pragma unroll
        for (int q = 0; q < 4; ++q) {
          float4 a = *(const float4*)(src + q * 8);
          float4 b = *(const float4*)(src + q * 8 + 4);
          v[q] = pack8(a, b);
        }
      } else {
        #pragma unroll
        for (int q = 0; q < 4; ++q) v[q] = (short8)(short)0;
      }
      #pragma unroll
      for (int q = 0; q < 4; ++q) *(short8*)&sA[p][sr][sh + q * 8] = v[q];
    }
    {
      const int f = n0 + sr;
      short8 v[4];
      if (f < NFR) {
        const int b = f / TFR, t = f - b * TFR;
        const float* xb = x + (size_t)b * LSIG;
        const int j0 = t * HOP + k0 + sh - 1024;
        if (j0 >= 0 && j0 + 32 <= LSIG) {
          #pragma unroll
          for (int q = 0; q < 4; ++q) {
            float4 a  = *(const float4*)(xb + j0 + q * 8);
            float4 b2 = *(const float4*)(xb + j0 + q * 8 + 4);
            v[q] = pack8(a, b2);
          }
        } else {
          #pragma unroll
          for (int q = 0; q < 4; ++q)
            #pragma unroll
            for (int e = 0; e < 8; ++e) {
              int j = j0 + q * 8 + e;
              j = j < 0 ? -j : (j >= LSIG ? 2 * LSIG - 2 - j : j);
              v[q][e] = bf16r(xb[j]);
            }
        }
      } else {
        #pragma unroll
        for (int q = 0; q < 4; ++q) v[q] = (short8)(short)0;
      }
      #pragma unroll
      for (int q = 0; q < 4; ++q) *(short8*)&sB[sr][sh + q * 8] = v[q];
    }
    __syncthreads();

    const int ra = lane & 15;
    #pragma unroll
    for (int kk = 0; kk < BK; kk += 32) {
      const int col = kk + (lane >> 4) * 8;
      short8 ar[4], ai[4], bfr[4];
      #pragma unroll
      for (int i = 0; i < 4; ++i) {
        const int rm = (wave >> 1) * 64 + i * 16 + ra;
        ar[i] = *(const short8*)&sA[0][rm][col];
        ai[i] = *(const short8*)&sA[1][rm][col];
        const int rn = (wave & 1) * 64 + i * 16 + ra;
        bfr[i] = *(const short8*)&sB[rn][col];
      }
      #pragma unroll
      for (int i = 0; i < 4; ++i)
        #pragma unroll
        for (int j = 0; j < 4; ++j) {
          acc_r[i][j] = __builtin_amdgcn_mfma_f32_16x16x32_bf16(ar[i], bfr[j], acc_r[i][j], 0, 0, 0);
          acc_i[i][j] = __builtin_amdgcn_mfma_f32_16x16x32_bf16(ai[i], bfr[j], acc_i[i][j], 0, 0, 0);
        }
    }
    __syncthreads();
  }

  const int wm0 = m0 + (wave >> 1) * 64;
  const int wn0 = n0 + (wave & 1) * 64;
  const int cl = lane & 15;
  const int rg = (lane >> 4) * 4;
  #pragma unroll
  for (int j = 0; j < 4; ++j) {
    const int f = wn0 + j * 16 + cl;
    if (f >= NFR) continue;
    const int b = f / TFR, t = f - b * TFR;
    float* ob = out + (size_t)b * (CUT * TFR) + t;
    #pragma unroll
    for (int i = 0; i < 4; ++i) {
      #pragma unroll
      for (int r = 0; r < 4; ++r) {
        const int k = wm0 + i * 16 + rg + r;
        if (k < CUT) {
          float re = acc_r[i][j][r], im = acc_i[i][j][r];
          ob[(size_t)k * TFR] = sqrtf(re * re + im * im);
        }
      }
    }
  }
}

extern "C" void kernel_launch(void* const* d_in, const int* in_sizes, int n_in,
                              void* d_out, int out_size, void* d_ws, size_t ws_size,
                              hipStream_t stream) {
  const float* x     = (const float*)d_in[0];
  const float* basis = (const float*)d_in[1];
  float* out = (float*)d_out;

  const size_t fbytes = (size_t)NPAD * FILT * sizeof(short);       // 82,837,504
  const size_t abytes = (size_t)2 * MPAD * FILT * sizeof(short);   //  9,437,184

  if (ws_size >= fbytes + abytes) {
    short* F = (short*)d_ws;
    short* A = (short*)((char*)d_ws + fbytes);
    build_frames<<<NPAD, 256, 0, stream>>>(x, F);
    convert_basis<<<2 * MPAD, 256, 0, stream>>>(basis, A);
    stft_gemm8<<<NWG, 512, 0, stream>>>(A, F, out);
  } else {
    stft_gemm_fb<<<dim3(157, 9), 256, 0, stream>>>(basis, x, out);
  }
}